// Round 14
// baseline (109.504 us; speedup 1.0000x reference)
//
#include <hip/hip_runtime.h>
#include <hip/hip_bf16.h>
#include <math.h>

#define BB   4
#define CC   256
#define DQK  32
#define NN   4096
#define QBLK 64
#define KVB  256
#define NQB  (NN / QBLK)
#define NTILES (NN / KVB)        // 16
#define SCALE 0.17677669529663687f   // 1/sqrt(32 + 1e-8)

typedef short  bf16x8 __attribute__((ext_vector_type(8)));
typedef float  f32x4  __attribute__((ext_vector_type(4)));
typedef unsigned short u16;
typedef unsigned int   u32;

__device__ __forceinline__ u16 f2bf(float f) {
    __hip_bfloat16 h = __float2bfloat16(f);   // round-to-nearest
    return *reinterpret_cast<u16*>(&h);
}

// ---------------------------------------------------------------------------
// Kernel 0: pack W -> bf16 [320][256] (Q rows & bias scaled), bias -> f32[320]
// ---------------------------------------------------------------------------
__global__ __launch_bounds__(256) void wprep_kernel(
    const float* __restrict__ Wq, const float* __restrict__ bq,
    const float* __restrict__ Wk, const float* __restrict__ bk,
    const float* __restrict__ Wv, const float* __restrict__ bv,
    u16* __restrict__ Wb, float* __restrict__ biasb)
{
    const int r = blockIdx.x;
    const int t = threadIdx.x;
    float w, bias;
    if (r < DQK)          { w = Wq[r * CC + t] * SCALE;     bias = bq[r] * SCALE; }
    else if (r < 2 * DQK) { w = Wk[(r - DQK) * CC + t];     bias = bk[r - DQK];  }
    else                  { w = Wv[(r - 2 * DQK) * CC + t]; bias = bv[r - 2 * DQK]; }
    Wb[r * CC + t] = f2bf(w);
    if (t == 0) biasb[r] = bias;
}

// ---------------------------------------------------------------------------
// Kernel 1: FUSED transpose + QKV MFMA GEMM: [320 x 256] @ [256 x 64-col tile].
// x f32 [B][C][N] staged into swizzled LDS xT[64 n][256 c] bf16.
// grid (NN/64, BB) = 256 blocks, block 512.
// ---------------------------------------------------------------------------
__global__ __launch_bounds__(512) void qkv_gemm(
    const float* __restrict__ x,
    const u16* __restrict__ Wb, const float* __restrict__ biasb,
    u16* __restrict__ qt, u16* __restrict__ kt, u16* __restrict__ v)
{
    __shared__ __align__(16) u16 xT[64][256];   // 32 KB, swizzled

    const int b   = blockIdx.y;
    const int n0  = blockIdx.x * 64;
    const int t   = threadIdx.x;

    // ---- stage x[b][0..256][n0..n0+64) -> xT (transpose + f32->bf16)
    {
        const int n_l = t & 63;          // local n
        const int cg  = t >> 6;          // 0..7
        const int sw  = (n_l & 15) << 3;
        #pragma unroll
        for (int p = 0; p < 8; ++p) {
            const int c0 = p * 32 + cg * 4;      // 4-aligned c
            const float f0 = x[((size_t)b * CC + c0 + 0) * NN + n0 + n_l];
            const float f1 = x[((size_t)b * CC + c0 + 1) * NN + n0 + n_l];
            const float f2 = x[((size_t)b * CC + c0 + 2) * NN + n0 + n_l];
            const float f3 = x[((size_t)b * CC + c0 + 3) * NN + n0 + n_l];
            uint2 pk;
            pk.x = (u32)f2bf(f0) | ((u32)f2bf(f1) << 16);
            pk.y = (u32)f2bf(f2) | ((u32)f2bf(f3) << 16);
            *(uint2*)&xT[n_l][c0 ^ sw] = pk;
        }
    }
    __syncthreads();

    const int wid = t >> 6;
    const int mw  = wid & 3;
    const int nw  = wid >> 2;
    const int lane = t & 63;
    const int g    = lane >> 4;
    const int c16  = lane & 15;

    f32x4 acc[5][2];
    #pragma unroll
    for (int mf = 0; mf < 5; ++mf)
        #pragma unroll
        for (int nf = 0; nf < 2; ++nf)
            #pragma unroll
            for (int r = 0; r < 4; ++r) acc[mf][nf][r] = 0.f;

    const int rsw = c16 << 3;

    #pragma unroll
    for (int kk = 0; kk < 8; ++kk) {
        bf16x8 xf[2];
        #pragma unroll
        for (int nf = 0; nf < 2; ++nf)
            xf[nf] = *(const bf16x8*)&xT[nw * 32 + nf * 16 + c16][(kk * 32 + g * 8) ^ rsw];
        #pragma unroll
        for (int mf = 0; mf < 5; ++mf) {
            const bf16x8 wf = *(const bf16x8*)(Wb + (size_t)(mw * 80 + mf * 16 + c16) * CC + kk * 32 + g * 8);
            #pragma unroll
            for (int nf = 0; nf < 2; ++nf)
                acc[mf][nf] = __builtin_amdgcn_mfma_f32_16x16x32_bf16(wf, xf[nf], acc[mf][nf], 0, 0, 0);
        }
    }

    #pragma unroll
    for (int mf = 0; mf < 5; ++mf) {
        #pragma unroll
        for (int nf = 0; nf < 2; ++nf) {
            const int n = n0 + nw * 32 + nf * 16 + c16;
            #pragma unroll
            for (int r = 0; r < 4; ++r) {
                const int row = mw * 80 + mf * 16 + g * 4 + r;
                const float val = acc[mf][nf][r] + biasb[row];
                if (row < DQK)
                    qt[((size_t)b * NN + n) * DQK + row] = f2bf(val);
                else if (row < 2 * DQK)
                    kt[((size_t)b * NN + n) * DQK + (row - DQK)] = f2bf(val);
                else
                    v[((size_t)b * CC + (row - 2 * DQK)) * NN + n] = f2bf(val);
            }
        }
    }
}

// ---------------------------------------------------------------------------
// Kernel 2: GEMM-shaped attention, NO-MAX softmax, KVB=256 big KV tile.
// Phase-count model (R3/R8/R9/R11: dur ~ 2.65us x barrier-phases/CU,
// nearly work-independent): halve phases 32 -> 16 by doubling KV tile.
// 8 waves. Wave wid = (mw = wid&3 q-group, jh = wid>>2 j-half-of-256):
//   QK: 8 MFMA (swapped mfma(K,Q), lane owns ONE q), 32 exp + l_acc,
//       8 packed b64 swizzled P-writes; kb[8] prefetched 1 tile ahead
//       (R3 precedent: kb[8] @ launch_bounds(512,2) = 112 VGPR, no spill).
//   PV: 64 MFMA, channels wid*32..+32, V inline per ksl (transient).
// One barrier/tile, P_s double-buffered 2x32KB. l: in-lane + 2 shfl + LDS.
// grid 256 (XCD-swizzled), block 512.
// ---------------------------------------------------------------------------
__global__ __launch_bounds__(512, 2) void attn_kernel(
    const u16* __restrict__ qt, const u16* __restrict__ kt,
    const u16* __restrict__ vg,
    const float* __restrict__ x, const float* __restrict__ gamma_p,
    float* __restrict__ out)
{
    const int id   = blockIdx.x;
    const int xcd  = id & 7;
    const int b    = xcd >> 1;
    const int i0   = (((xcd & 1) << 5) + (id >> 3)) * QBLK;
    const int t    = threadIdx.x;
    const int wid  = t >> 6;        // 0..7
    const int lane = t & 63;
    const int g    = lane >> 4;
    const int c16  = lane & 15;
    const int jh   = wid >> 2;      // j-half 0/1 (each 128 of the 256)
    const int mw   = wid & 3;       // q-group

    __shared__ __align__(16) u16 P_s[2][QBLK * KVB];   // 2 x 32 KB, XOR-swizzled
    __shared__ float l_s[2][QBLK];

    const u16* ktb = kt + (size_t)b * NN * DQK;
    const u16* vb  = vg + (size_t)b * CC * NN + (size_t)(wid * 32) * NN;

    // B-frag Q (q = i0 + mw*16 + c16)
    const bf16x8 qa = *(const bf16x8*)(qt + ((size_t)b * NN + i0 + mw * 16 + c16) * DQK + g * 8);

    // K tile 0, this wave's j-half: rows j = jh*128 + jf*16 + c16
    bf16x8 kb[8];
    #pragma unroll
    for (int jf = 0; jf < 8; ++jf)
        kb[jf] = *(const bf16x8*)(ktb + (size_t)(jh * 128 + jf * 16 + c16) * DQK + g * 8);

    f32x4 accv[2][4];   // [cf][qf]: channels wid*32+cf*16.., q cols qf*16..
    #pragma unroll
    for (int cf = 0; cf < 2; ++cf)
        #pragma unroll
        for (int qf = 0; qf < 4; ++qf)
            #pragma unroll
            for (int r = 0; r < 4; ++r) accv[cf][qf][r] = 0.f;

    float l_acc = 0.f;   // running denom for this lane's q (its 32-j slice/tile)

    for (int jt = 0; jt < NTILES; ++jt) {
        const int j0  = jt * KVB;
        const int buf = jt & 1;

        // ---- S^T = K Q^T for this wave's (q-group, j-half)
        f32x4 sres[8];
        #pragma unroll
        for (int jf = 0; jf < 8; ++jf)
            sres[jf] = __builtin_amdgcn_mfma_f32_16x16x32_bf16(kb[jf], qa, (f32x4){0.f, 0.f, 0.f, 0.f}, 0, 0, 0);

        // ---- prefetch next K tile (lands under exp/pack + PV)
        const int jn = ((jt + 1) & (NTILES - 1)) * KVB;
        #pragma unroll
        for (int jf = 0; jf < 8; ++jf)
            kb[jf] = *(const bf16x8*)(ktb + (size_t)(jn + jh * 128 + jf * 16 + c16) * DQK + g * 8);

        // ---- P = exp(S) -> bf16 (no max-sub), accumulate l, packed writes
        {
            const int rowbase = (mw * 16 + c16) * KVB;
            const int swz     = c16 << 3;
            #pragma unroll
            for (int jf = 0; jf < 8; ++jf) {
                const float p0 = __expf(sres[jf][0]);
                const float p1 = __expf(sres[jf][1]);
                const float p2 = __expf(sres[jf][2]);
                const float p3 = __expf(sres[jf][3]);
                l_acc += (p0 + p1) + (p2 + p3);
                u32 lo = (u32)f2bf(p0) | ((u32)f2bf(p1) << 16);
                u32 hi = (u32)f2bf(p2) | ((u32)f2bf(p3) << 16);
                uint2 pk; pk.x = lo; pk.y = hi;
                *(uint2*)&P_s[buf][rowbase + ((jh * 128 + jf * 16 + g * 4) ^ swz)] = pk;
            }
        }
        __syncthreads();   // P_s[buf] ready (also fences prev-tile PV reads)

        // ---- PV: O^T[c][q] += V[c][j] * P[q][j]; V inline per ksl
        __builtin_amdgcn_s_setprio(1);
        #pragma unroll
        for (int ksl = 0; ksl < 8; ++ksl) {
            const bf16x8 va0 = *(const bf16x8*)(vb + (size_t)(c16) * NN + j0 + ksl * 32 + g * 8);
            const bf16x8 va1 = *(const bf16x8*)(vb + (size_t)(16 + c16) * NN + j0 + ksl * 32 + g * 8);
            #pragma unroll
            for (int qf = 0; qf < 4; ++qf) {
                const int row = c16 + 16 * qf;
                const int e   = (row * KVB + ksl * 32 + g * 8) ^ ((row & 15) << 3);
                const bf16x8 pb = *(const bf16x8*)&P_s[buf][e];
                accv[0][qf] = __builtin_amdgcn_mfma_f32_16x16x32_bf16(va0, pb, accv[0][qf], 0, 0, 0);
                accv[1][qf] = __builtin_amdgcn_mfma_f32_16x16x32_bf16(va1, pb, accv[1][qf], 0, 0, 0);
            }
        }
        __builtin_amdgcn_s_setprio(0);
    }

    // ---- finalize denominator: reduce over g, combine the two j-halves
    l_acc += __shfl_xor(l_acc, 16);
    l_acc += __shfl_xor(l_acc, 32);
    if (lane < 16) l_s[jh][mw * 16 + c16] = l_acc;   // lane<16 <=> g==0
    __syncthreads();

    // ---- epilogue: out = gamma * O / l + x
    const float gam = gamma_p[0];
    #pragma unroll
    for (int qf = 0; qf < 4; ++qf) {
        const int   qloc = c16 + 16 * qf;
        const int   qcol = i0 + qloc;
        const float linv = 1.0f / (l_s[0][qloc] + l_s[1][qloc]);
        #pragma unroll
        for (int cf = 0; cf < 2; ++cf) {
            #pragma unroll
            for (int r = 0; r < 4; ++r) {
                const int    c = wid * 32 + cf * 16 + g * 4 + r;
                const size_t o = ((size_t)b * CC + c) * NN + qcol;
                out[o] = gam * (accv[cf][qf][r] * linv) + x[o];
            }
        }
    }
}

// ---------------------------------------------------------------------------
extern "C" void kernel_launch(void* const* d_in, const int* in_sizes, int n_in,
                              void* d_out, int out_size, void* d_ws, size_t ws_size,
                              hipStream_t stream)
{
    const float* x     = (const float*)d_in[0];
    const float* Wq    = (const float*)d_in[1];
    const float* bq    = (const float*)d_in[2];
    const float* Wk    = (const float*)d_in[3];
    const float* bk    = (const float*)d_in[4];
    const float* Wv    = (const float*)d_in[5];
    const float* bv    = (const float*)d_in[6];
    const float* gamma = (const float*)d_in[7];
    float* out = (float*)d_out;

    // workspace: Qt 1M | Kt 1M | V 8M | Wb 160K | biasb  (~10.5 MB)
    u16* qt   = (u16*)d_ws;
    u16* kt   = qt + (size_t)BB * NN * DQK;
    u16* v    = kt + (size_t)BB * NN * DQK;
    u16* Wb   = v  + (size_t)BB * CC * NN;
    float* biasb = (float*)(Wb + 320 * CC);

    wprep_kernel<<<dim3(320), 256, 0, stream>>>(Wq, bq, Wk, bk, Wv, bv, Wb, biasb);
    qkv_gemm<<<dim3(NN / 64, BB), 512, 0, stream>>>(x, Wb, biasb, qt, kt, v);
    attn_kernel<<<dim3(BB * NQB), 512, 0, stream>>>(qt, kt, v, x, gamma, out);
}